// Round 2
// baseline (302.312 us; speedup 1.0000x reference)
//
#include <hip/hip_runtime.h>
#include <hip/hip_bf16.h>

// CTC batch cost forward pass — single-wave-per-batch-element, barrier-free.
// B=1024, T=256, C=128, L=32, S=65, blank=127.
// Lane i (i<=32) holds alpha[2i] ("lo") and alpha[2i+1] ("hi") in registers.
// Shifts s-1/s-2 are __shfl_up; emission gather is ds_bpermute on the
// register-held prob row (lane j holds p[2j], p[2j+1]); blank emission is a
// single broadcast since all even states are blank.

#define CTC_B 1024
#define CTC_T 256
#define CTC_C 128
#define CTC_L 32
#define CTC_S 65
#define CTC_BLANK 127
#define NEG_INF (-1e30f)
#define CTC_EPS 1e-7f

__device__ __forceinline__ float lse3(float a0, float a1, float a2) {
    float m = fmaxf(a0, fmaxf(a1, a2));
    return m + __logf(__expf(a0 - m) + __expf(a1 - m) + __expf(a2 - m));
}

__device__ __forceinline__ float bperm(int byte_addr, float v) {
    return __int_as_float(__builtin_amdgcn_ds_bpermute(byte_addr, __float_as_int(v)));
}

__global__ __launch_bounds__(64) void ctc_loss_kernel(
    const int* __restrict__ y_true,   // [B, L] int32
    const float* __restrict__ y_pred, // [B, T, C] float32
    float* __restrict__ out)          // [B, 1] float32
{
    const int b = blockIdx.x;
    const int lane = threadIdx.x;
    const float2* yp = (const float2*)(y_pred + (size_t)b * CTC_T * CTC_C);

    // --- per-lane constants: odd-state label + skip permission ---
    int ext_hi = CTC_BLANK;          // label for state 2*lane+1
    float skip_hi = NEG_INF;         // s-2 skip allowed for that state?
    if (lane < CTC_L) {
        ext_hi = y_true[b * CTC_L + lane];
        if (lane >= 1) {
            int prev = y_true[b * CTC_L + lane - 1];
            if (prev != ext_hi) skip_hi = 0.0f;   // labels never == blank here
        }
    }
    const int gaddr = (ext_hi >> 1) << 2;  // bpermute byte addr: source lane*4
    const bool godd = (ext_hi & 1);

    // --- t = 0: init ---
    float2 p0 = yp[lane];
    float lpb0 = __logf(__shfl(p0.y, 63) + CTC_EPS);              // log p[blank]
    {
        // only lane 0 needs its odd gather at t=0, but run uniformly
    }
    float ge0 = bperm(gaddr, p0.x);
    float go0 = bperm(gaddr, p0.y);
    float lph0 = __logf((godd ? go0 : ge0) + CTC_EPS);

    float lo = (lane == 0) ? lpb0 : NEG_INF;   // alpha[0] = log p0[blank]
    float hi = (lane == 0) ? lph0 : NEG_INF;   // alpha[1] = log p0[y0]

    // --- prefetch pipeline (distance 2) ---
    float2 pN  = yp[1 * (CTC_C / 2) + lane];   // data for t=1
    float2 pN2 = yp[2 * (CTC_C / 2) + lane];   // data for t=2

    for (int t = 1; t < CTC_T; ++t) {
        // emission log-probs for this t (independent of alpha chain)
        float lp_blank = __logf(__shfl(pN.y, 63) + CTC_EPS);
        float ge = bperm(gaddr, pN.x);
        float go = bperm(gaddr, pN.y);
        float lp_hi = __logf((godd ? go : ge) + CTC_EPS);

        pN = pN2;
        int tn = (t + 2 < CTC_T) ? (t + 2) : (CTC_T - 1);
        pN2 = yp[tn * (CTC_C / 2) + lane];

        // neighbor alphas from lane-1
        float pl = __shfl_up(lo, 1);   // alpha[2i-2]
        float ph = __shfl_up(hi, 1);   // alpha[2i-1]
        if (lane == 0) { pl = NEG_INF; ph = NEG_INF; }

        // even state 2i: blank -> no skip (a2 = NEG_INF exactly, as in ref)
        float nl = lse3(lo, ph, NEG_INF) + lp_blank;
        nl = fmaxf(nl, NEG_INF);
        // odd state 2i+1: a0=hi, a1=lo(old), a2=alpha[2i-1]+skip
        float a2h = fmaxf(ph + skip_hi, NEG_INF);
        float nh = lse3(hi, lo, a2h) + lp_hi;
        nh = fmaxf(nh, NEG_INF);

        lo = nl;
        hi = nh;
    }

    // --- epilogue: -logaddexp(alpha[S-1], alpha[S-2]) ---
    float aS1 = __shfl(lo, 32);  // alpha[64]
    float aS2 = __shfl(hi, 31);  // alpha[63]
    if (lane == 0) {
        float m = fmaxf(aS1, aS2);
        out[b] = -(m + __logf(__expf(aS1 - m) + __expf(aS2 - m)));
    }
}

extern "C" void kernel_launch(void* const* d_in, const int* in_sizes, int n_in,
                              void* d_out, int out_size, void* d_ws, size_t ws_size,
                              hipStream_t stream) {
    const int*   y_true = (const int*)d_in[0];
    const float* y_pred = (const float*)d_in[1];
    float*       out    = (float*)d_out;

    ctc_loss_kernel<<<CTC_B, 64, 0, stream>>>(y_true, y_pred, out);
}

// Round 4
// 231.564 us; speedup vs baseline: 1.3055x; 1.3055x over previous
//
#include <hip/hip_runtime.h>
#include <hip/hip_bf16.h>

// CTC batch cost — split-phase: memory-throughput phase fills a compact LDS
// table of log-probs; a single wave then runs the latency-bound recurrence
// with one ds_bpermute per step and all emission values pre-staged in LDS.
// B=1024, T=256, C=128, L=32, S=65, blank=127.

#define CTC_B 1024
#define CTC_T 256
#define CTC_C 128
#define CTC_L 32
#define CTC_BLANK 127
#define NEG_INF (-1e30f)
#define CTC_EPS 1e-7f

#define RSTRIDE 33   // 32 labels + 1 blank per timestep

__global__ __launch_bounds__(256) void ctc_loss_kernel(
    const int* __restrict__ y_true,   // [B, L] int32
    const float* __restrict__ y_pred, // [B, T, C] float32
    float* __restrict__ out)          // [B, 1] float32
{
    __shared__ float lp[CTC_T * RSTRIDE];  // 33.8 KB -> 4 blocks/CU

    const int b = blockIdx.x;
    const int tid = threadIdx.x;
    const int lane = tid & 63;
    const int wave = tid >> 6;

    const float* yp = y_pred + (size_t)b * CTC_T * CTC_C;

    // per-lane gather label: lanes 0..31 -> y_true, lanes 32..63 -> blank
    int lbl = CTC_BLANK;
    if (lane < CTC_L) lbl = y_true[b * CTC_L + lane];

    // ---- phase 1: 4 waves fill lp[t][j] = log(p[t][ext_j] + eps) ----
    // wave w handles t in [w*64, w*64+64). Loads are independent: deep queue.
    {
        const int t0 = wave * 64;
        #pragma unroll 8
        for (int k = 0; k < 64; ++k) {
            int t = t0 + k;
            float p = yp[t * CTC_C + lbl];       // gather within 512B row
            float v = __logf(p + CTC_EPS);
            if (lane <= 32) lp[t * RSTRIDE + lane] = v;
        }
    }
    __syncthreads();

    if (wave != 0) return;

    // ---- phase 2: wave 0, lane i owns alpha[2i] (lo) and alpha[2i+1] (hi).
    float skip_hi = NEG_INF;
    if (lane >= 1 && lane < CTC_L) {
        int prev = y_true[b * CTC_L + lane - 1];
        if (prev != lbl) skip_hi = 0.0f;   // labels are never blank
    }
    const int lidx = (lane < 32) ? lane : 32;   // lanes>=32 read blank slot
    const int up_addr = (lane - 1) << 2;        // bpermute addr (lane0 masked)

    float lo = (lane == 0) ? lp[32] : NEG_INF;  // alpha[0] = blank @ t=0
    float hi = (lane == 0) ? lp[0]  : NEG_INF;  // alpha[1] = label0 @ t=0

    // software-pipelined LDS reads (addresses independent of the chain)
    float lpv = lp[RSTRIDE + lidx];
    float lpb = lp[RSTRIDE + 32];

    for (int t = 1; t < CTC_T; ++t) {
        float lpv_n = 0.f, lpb_n = 0.f;
        if (t + 1 < CTC_T) {
            lpv_n = lp[(t + 1) * RSTRIDE + lidx];
            lpb_n = lp[(t + 1) * RSTRIDE + 32];
        }

        // the ONLY cross-lane op on the chain: alpha[2i-1] from lane i-1
        float ph = __int_as_float(__builtin_amdgcn_ds_bpermute(
                       up_addr, __float_as_int(hi)));
        if (lane == 0) ph = NEG_INF;

        // even state 2i (blank): lse(lo, ph) + lp_blank
        float m0 = fmaxf(lo, ph);
        float nl = m0 + __logf(__expf(lo - m0) + __expf(ph - m0)) + lpb;
        nl = fmaxf(nl, NEG_INF);

        // odd state 2i+1: lse(hi, lo, ph + skip) + lp_label
        float a2 = fmaxf(ph + skip_hi, NEG_INF);
        float m1 = fmaxf(hi, fmaxf(lo, a2));
        float nh = m1 + __logf(__expf(hi - m1) + __expf(lo - m1) +
                               __expf(a2 - m1)) + lpv;
        nh = fmaxf(nh, NEG_INF);

        lo = nl; hi = nh;
        lpv = lpv_n; lpb = lpb_n;
    }

    // loss = -logaddexp(alpha[64], alpha[63])
    float aS1 = __shfl(lo, 32);
    float aS2 = __shfl(hi, 31);
    if (lane == 0) {
        float m = fmaxf(aS1, aS2);
        out[b] = -(m + __logf(__expf(aS1 - m) + __expf(aS2 - m)));
    }
}

extern "C" void kernel_launch(void* const* d_in, const int* in_sizes, int n_in,
                              void* d_out, int out_size, void* d_ws, size_t ws_size,
                              hipStream_t stream) {
    const int*   y_true = (const int*)d_in[0];
    const float* y_pred = (const float*)d_in[1];
    float*       out    = (float*)d_out;

    ctc_loss_kernel<<<CTC_B, 256, 0, stream>>>(y_true, y_pred, out);
}